// Round 1
// baseline (351.904 us; speedup 1.0000x reference)
//
#include <hip/hip_runtime.h>

// Problem constants (roberta-base vocab / fixed harness shapes).
constexpr int T_VOCAB = 50265;  // vocab size
constexpr int CLEN    = 384;    // context length
constexpr int BSZ     = 4;      // batch
constexpr int NDATA   = 2048;   // dataset rows
constexpr int NPT     = NDATA / 256;  // pairs per thread in scatter (8)
constexpr int CHUNK   = 12672;  // floats per LDS chunk (49.5 KB -> 3 blocks/CU, 4 chunks cover 50265)

// ---------------------------------------------------------------------------
// K1: per dataset row n, compute match counts vs all BSZ input rows, emit
// logp[b][n] = mc*log_a[b] + (CLEN-mc)*log_b[b].  Optionally also write the
// dataset transpose dsT[s][n] so the scatter kernel's column loads coalesce.
// ---------------------------------------------------------------------------
template <bool WRITE_T>
__global__ __launch_bounds__(256) void k_match_logp(
    const int* __restrict__ in_tok,   // [BSZ][CLEN]
    const int* __restrict__ ds_tok,   // [NDATA][CLEN]
    const float* __restrict__ t,      // [BSZ]
    float* __restrict__ logp,         // [BSZ][NDATA]
    int* __restrict__ dsT)            // [CLEN][NDATA] (optional)
{
    __shared__ int s_in[BSZ * CLEN];
    __shared__ float s_la[BSZ], s_lb[BSZ];
    const int tid = threadIdx.x;
    for (int i = tid; i < BSZ * CLEN; i += 256) s_in[i] = in_tok[i];
    if (tid < BSZ) {
        float tv = t[tid];
        s_la[tid] = logf(tv + (1.0f - tv) / (float)T_VOCAB);
        s_lb[tid] = logf((1.0f - tv) / (float)T_VOCAB);
    }
    __syncthreads();

    const int n = blockIdx.x * 256 + tid;   // grid = NDATA/256 blocks
    int mc0 = 0, mc1 = 0, mc2 = 0, mc3 = 0;
    const int4* row = (const int4*)(ds_tok + (size_t)n * CLEN);
    #pragma unroll 8
    for (int j = 0; j < CLEN / 4; ++j) {
        int4 v = row[j];
        int s = 4 * j;
        if (WRITE_T) {
            // lanes hold consecutive n at fixed s -> coalesced dword stores
            dsT[(size_t)(s + 0) * NDATA + n] = v.x;
            dsT[(size_t)(s + 1) * NDATA + n] = v.y;
            dsT[(size_t)(s + 2) * NDATA + n] = v.z;
            dsT[(size_t)(s + 3) * NDATA + n] = v.w;
        }
        mc0 += (v.x == s_in[0*CLEN+s]) + (v.y == s_in[0*CLEN+s+1]) + (v.z == s_in[0*CLEN+s+2]) + (v.w == s_in[0*CLEN+s+3]);
        mc1 += (v.x == s_in[1*CLEN+s]) + (v.y == s_in[1*CLEN+s+1]) + (v.z == s_in[1*CLEN+s+2]) + (v.w == s_in[1*CLEN+s+3]);
        mc2 += (v.x == s_in[2*CLEN+s]) + (v.y == s_in[2*CLEN+s+1]) + (v.z == s_in[2*CLEN+s+2]) + (v.w == s_in[2*CLEN+s+3]);
        mc3 += (v.x == s_in[3*CLEN+s]) + (v.y == s_in[3*CLEN+s+1]) + (v.z == s_in[3*CLEN+s+2]) + (v.w == s_in[3*CLEN+s+3]);
    }
    float m;
    m = (float)mc0; logp[0 * NDATA + n] = m * s_la[0] + ((float)CLEN - m) * s_lb[0];
    m = (float)mc1; logp[1 * NDATA + n] = m * s_la[1] + ((float)CLEN - m) * s_lb[1];
    m = (float)mc2; logp[2 * NDATA + n] = m * s_la[2] + ((float)CLEN - m) * s_lb[2];
    m = (float)mc3; logp[3 * NDATA + n] = m * s_la[3] + ((float)CLEN - m) * s_lb[3];
}

// ---------------------------------------------------------------------------
// K2: stable softmax over the dataset axis, one block per b.
// ---------------------------------------------------------------------------
__global__ __launch_bounds__(256) void k_softmax(
    const float* __restrict__ logp,  // [BSZ][NDATA]
    float* __restrict__ w)           // [BSZ][NDATA]
{
    const int b = blockIdx.x;
    const int tid = threadIdx.x;
    float lp[NPT];
    float m = -INFINITY;
    #pragma unroll
    for (int k = 0; k < NPT; ++k) {
        lp[k] = logp[b * NDATA + tid + k * 256];
        m = fmaxf(m, lp[k]);
    }
    #pragma unroll
    for (int off = 32; off >= 1; off >>= 1) m = fmaxf(m, __shfl_xor(m, off));
    __shared__ float redm[4];
    __shared__ float reds[4];
    const int wid = tid >> 6;
    if ((tid & 63) == 0) redm[wid] = m;
    __syncthreads();
    const float M = fmaxf(fmaxf(redm[0], redm[1]), fmaxf(redm[2], redm[3]));

    float e[NPT];
    float sum = 0.0f;
    #pragma unroll
    for (int k = 0; k < NPT; ++k) { e[k] = expf(lp[k] - M); sum += e[k]; }
    #pragma unroll
    for (int off = 32; off >= 1; off >>= 1) sum += __shfl_xor(sum, off);
    if ((tid & 63) == 0) reds[wid] = sum;
    __syncthreads();
    const float inv = 1.0f / (reds[0] + reds[1] + reds[2] + reds[3]);
    #pragma unroll
    for (int k = 0; k < NPT; ++k) w[b * NDATA + tid + k * 256] = e[k] * inv;
}

// ---------------------------------------------------------------------------
// K3: one block per output row (b, s).  Build the 50265-float row in LDS
// chunks (LDS atomicAdd handles duplicate tokens), stream each chunk to
// global with aligned float4 stores.  Output written exactly once.
// ---------------------------------------------------------------------------
template <bool USE_T>
__global__ __launch_bounds__(256) void k_scatter(
    const int* __restrict__ ds_tok,  // [NDATA][CLEN]
    const int* __restrict__ dsT,     // [CLEN][NDATA]
    const float* __restrict__ w,     // [BSZ][NDATA]
    float* __restrict__ out)         // [BSZ][CLEN][T_VOCAB]
{
    __shared__ float lds[CHUNK];
    const int tid = threadIdx.x;
    const int bid = blockIdx.x;          // grid = BSZ*CLEN, b minor
    const int b = bid & (BSZ - 1);
    const int s = bid >> 2;

    int   tok[NPT];
    float wv[NPT];
    #pragma unroll
    for (int k = 0; k < NPT; ++k) {
        const int n = tid + k * 256;
        tok[k] = USE_T ? dsT[(size_t)s * NDATA + n]
                       : ds_tok[(size_t)n * CLEN + s];
        wv[k] = w[b * NDATA + n];
    }

    float* rowp = out + ((size_t)b * CLEN + s) * T_VOCAB;
    const size_t row_elem0 = ((size_t)b * CLEN + s) * (size_t)T_VOCAB;

    for (int c0 = 0; c0 < T_VOCAB; c0 += CHUNK) {
        const int nch = (T_VOCAB - c0 < CHUNK) ? (T_VOCAB - c0) : CHUNK;
        for (int i = tid; i < nch; i += 256) lds[i] = 0.0f;
        __syncthreads();
        #pragma unroll
        for (int k = 0; k < NPT; ++k) {
            const unsigned off = (unsigned)(tok[k] - c0);
            if (off < (unsigned)nch) atomicAdd(&lds[off], wv[k]);
        }
        __syncthreads();
        // ---- stream chunk to global, 16B-aligned float4 main body ----
        const unsigned g0mod = (unsigned)((row_elem0 + (size_t)c0) & 3u);
        int head = (int)((4u - g0mod) & 3u);
        if (head > nch) head = nch;
        if (tid < head) rowp[c0 + tid] = lds[tid];
        const int rem = nch - head;
        const int nv = rem >> 2;
        float4* dst4 = (float4*)(rowp + c0 + head);
        for (int i = tid; i < nv; i += 256) {
            const int j = head + 4 * i;
            float4 v = { lds[j], lds[j + 1], lds[j + 2], lds[j + 3] };
            dst4[i] = v;
        }
        const int ts = head + (nv << 2);
        for (int i = ts + tid; i < nch; i += 256) rowp[c0 + i] = lds[i];
        __syncthreads();  // protect lds reuse across chunks
    }
}

// ---------------------------------------------------------------------------
extern "C" void kernel_launch(void* const* d_in, const int* in_sizes, int n_in,
                              void* d_out, int out_size, void* d_ws, size_t ws_size,
                              hipStream_t stream) {
    const int*   in_tok = (const int*)d_in[0];    // (BSZ, CLEN) int32
    const int*   ds_tok = (const int*)d_in[1];    // (NDATA, CLEN) int32
    const float* t      = (const float*)d_in[2];  // (BSZ,) f32
    float* out = (float*)d_out;                   // (BSZ, CLEN, T_VOCAB) f32

    float* logp = (float*)d_ws;                   // BSZ*NDATA
    float* w    = logp + (size_t)BSZ * NDATA;     // BSZ*NDATA
    int*   dsT  = (int*)(w + (size_t)BSZ * NDATA);// CLEN*NDATA

    const size_t need = (size_t)2 * BSZ * NDATA * sizeof(float)
                      + (size_t)CLEN * NDATA * sizeof(int);
    const bool use_t = ws_size >= need;

    if (use_t) {
        k_match_logp<true><<<NDATA / 256, 256, 0, stream>>>(in_tok, ds_tok, t, logp, dsT);
    } else {
        k_match_logp<false><<<NDATA / 256, 256, 0, stream>>>(in_tok, ds_tok, t, logp, dsT);
    }
    k_softmax<<<BSZ, 256, 0, stream>>>(logp, w);
    if (use_t) {
        k_scatter<true><<<BSZ * CLEN, 256, 0, stream>>>(ds_tok, dsT, w, out);
    } else {
        k_scatter<false><<<BSZ * CLEN, 256, 0, stream>>>(ds_tok, dsT, w, out);
    }
}

// Round 3
// 344.439 us; speedup vs baseline: 1.0217x; 1.0217x over previous
//
#include <hip/hip_runtime.h>

// Problem constants (fixed harness shapes).
constexpr int T_VOCAB = 50265;          // vocab size
constexpr int CLEN    = 384;            // context length
constexpr int BSZ     = 4;              // batch
constexpr int NDATA   = 2048;           // dataset rows
constexpr int NPT     = NDATA / 256;    // dataset rows per thread (8)
constexpr int CHUNK   = 6720;           // floats per LDS chunk (26.3 KB -> 6 blocks/CU, grid fully resident)
constexpr int SLICES  = 8;              // s-slices in the match kernel
constexpr int SCOLS   = CLEN / SLICES;  // 48 columns per slice

typedef float f32x4 __attribute__((ext_vector_type(4)));  // native vector: OK for nontemporal builtins

// ---------------------------------------------------------------------------
// K0: LDS-tiled transpose ds_tok[N][S] -> dsT[S][N].  3 MB each way, ~2 us.
// ---------------------------------------------------------------------------
__global__ __launch_bounds__(256) void k_transpose(
    const int* __restrict__ ds, int* __restrict__ dsT)
{
    __shared__ int tile[64][65];                 // +1 pad: conflict-free
    const int n0 = blockIdx.x * 64;              // 32 n-tiles
    const int s0 = blockIdx.y * 64;              // 6 s-tiles
    const int lane = threadIdx.x & 63;
    const int quad = threadIdx.x >> 6;           // 0..3
    #pragma unroll
    for (int k = 0; k < 16; ++k) {
        const int r = quad + 4 * k;
        tile[r][lane] = ds[(size_t)(n0 + r) * CLEN + s0 + lane];
    }
    __syncthreads();
    #pragma unroll
    for (int k = 0; k < 16; ++k) {
        const int c = quad + 4 * k;
        dsT[(size_t)(s0 + c) * NDATA + n0 + lane] = tile[lane][c];
    }
}

// ---------------------------------------------------------------------------
// K1: partial match counts per (s-slice, b, n).  64 blocks, coalesced dsT
// loads, lane-uniform input-token operands (scalarized by the compiler).
// ---------------------------------------------------------------------------
__global__ __launch_bounds__(256) void k_match(
    const int* __restrict__ dsT,      // [CLEN][NDATA]
    const int* __restrict__ in_tok,   // [BSZ][CLEN]
    int* __restrict__ pcount)         // [SLICES][BSZ][NDATA]
{
    const int nt = blockIdx.x & 7;    // 8 n-tiles of 256
    const int sl = blockIdx.x >> 3;   // 8 s-slices of 48
    const int n  = nt * 256 + threadIdx.x;
    const int sbase = sl * SCOLS;
    int c0 = 0, c1 = 0, c2 = 0, c3 = 0;
    #pragma unroll 4
    for (int j = 0; j < SCOLS; ++j) {
        const int s = sbase + j;
        const int tok = dsT[(size_t)s * NDATA + n];   // coalesced
        c0 += (tok == in_tok[0 * CLEN + s]);          // uniform -> SGPR
        c1 += (tok == in_tok[1 * CLEN + s]);
        c2 += (tok == in_tok[2 * CLEN + s]);
        c3 += (tok == in_tok[3 * CLEN + s]);
    }
    pcount[(sl * BSZ + 0) * NDATA + n] = c0;
    pcount[(sl * BSZ + 1) * NDATA + n] = c1;
    pcount[(sl * BSZ + 2) * NDATA + n] = c2;
    pcount[(sl * BSZ + 3) * NDATA + n] = c3;
}

// ---------------------------------------------------------------------------
// K2: reduce partial counts -> logp -> stable softmax -> w.  One block per b.
// ---------------------------------------------------------------------------
__global__ __launch_bounds__(256) void k_weights(
    const int* __restrict__ pcount,   // [SLICES][BSZ][NDATA]
    const float* __restrict__ t,      // [BSZ]
    float* __restrict__ w)            // [BSZ][NDATA]
{
    const int b = blockIdx.x;
    const int tid = threadIdx.x;
    const float tv = t[b];
    const float la = logf(tv + (1.0f - tv) / (float)T_VOCAB);
    const float lb = logf((1.0f - tv) / (float)T_VOCAB);

    float lp[NPT];
    float m = -INFINITY;
    #pragma unroll
    for (int k = 0; k < NPT; ++k) {
        const int n = tid + k * 256;
        int cnt = 0;
        #pragma unroll
        for (int sl = 0; sl < SLICES; ++sl)
            cnt += pcount[(sl * BSZ + b) * NDATA + n];
        const float mc = (float)cnt;
        lp[k] = mc * la + ((float)CLEN - mc) * lb;
        m = fmaxf(m, lp[k]);
    }
    #pragma unroll
    for (int off = 32; off >= 1; off >>= 1) m = fmaxf(m, __shfl_xor(m, off));
    __shared__ float redm[4], reds[4];
    const int wid = tid >> 6;
    if ((tid & 63) == 0) redm[wid] = m;
    __syncthreads();
    const float M = fmaxf(fmaxf(redm[0], redm[1]), fmaxf(redm[2], redm[3]));

    float e[NPT];
    float sum = 0.0f;
    #pragma unroll
    for (int k = 0; k < NPT; ++k) { e[k] = expf(lp[k] - M); sum += e[k]; }
    #pragma unroll
    for (int off = 32; off >= 1; off >>= 1) sum += __shfl_xor(sum, off);
    if ((tid & 63) == 0) reds[wid] = sum;
    __syncthreads();
    const float inv = 1.0f / (reds[0] + reds[1] + reds[2] + reds[3]);
    #pragma unroll
    for (int k = 0; k < NPT; ++k) w[b * NDATA + tid + k * 256] = e[k] * inv;
}

// ---------------------------------------------------------------------------
// K3: one block per output row (b, s).  Build the 50265-float row in 8 LDS
// chunks; LDS atomicAdd handles duplicate tokens; stream each chunk with
// 16B-aligned nontemporal f32x4 stores (alignment fixed via align_off so
// LDS and global float4 alignment coincide).  Output written exactly once.
// ---------------------------------------------------------------------------
template <bool USE_T>
__global__ __launch_bounds__(256) void k_scatter(
    const int* __restrict__ ds_tok,  // [NDATA][CLEN]
    const int* __restrict__ dsT,     // [CLEN][NDATA]
    const float* __restrict__ w,     // [BSZ][NDATA]
    float* __restrict__ out)         // [BSZ][CLEN][T_VOCAB]
{
    __shared__ float lds[CHUNK + 4];
    const int tid = threadIdx.x;
    const int bid = blockIdx.x;          // grid = BSZ*CLEN, b minor (shared s -> L2 reuse)
    const int b = bid & (BSZ - 1);
    const int s = bid >> 2;

    int   tok[NPT];
    float wv[NPT];
    #pragma unroll
    for (int k = 0; k < NPT; ++k) {
        const int n = tid + k * 256;
        tok[k] = USE_T ? dsT[(size_t)s * NDATA + n]      // coalesced
                       : ds_tok[(size_t)n * CLEN + s];   // fallback, scattered
        wv[k] = w[b * NDATA + n];
    }

    const size_t row_elem0 = ((size_t)b * CLEN + s) * (size_t)T_VOCAB;
    float* rowp = out + row_elem0;
    const int align_off = (int)(row_elem0 & 3);  // lds[j+align_off] <-> row elem c0+j

    for (int c0 = 0; c0 < T_VOCAB; c0 += CHUNK) {
        const int nch = (T_VOCAB - c0 < CHUNK) ? (T_VOCAB - c0) : CHUNK;
        const int tot = nch + align_off;
        // ---- zero LDS (vectorized) ----
        f32x4* l4 = (f32x4*)lds;
        const int nz4 = (tot + 3) >> 2;
        for (int i = tid; i < nz4; i += 256) l4[i] = (f32x4){0.f, 0.f, 0.f, 0.f};
        __syncthreads();
        // ---- scatter this block's 2048 (token, weight) pairs ----
        #pragma unroll
        for (int k = 0; k < NPT; ++k) {
            const unsigned off = (unsigned)(tok[k] - c0);
            if (off < (unsigned)nch) atomicAdd(&lds[off + align_off], wv[k]);
        }
        __syncthreads();
        // ---- stream chunk to global: scalar head, aligned f32x4 body, tail ----
        int head = (4 - align_off) & 3;
        if (head > nch) head = nch;
        if (tid < head) rowp[c0 + tid] = lds[tid + align_off];
        const int nv = (nch - head) >> 2;
        const f32x4* l4s = (const f32x4*)lds + (align_off ? 1 : 0);
        f32x4* dst4 = (f32x4*)(rowp + c0 + head);
        for (int i = tid; i < nv; i += 256)
            __builtin_nontemporal_store(l4s[i], &dst4[i]);
        const int ts = head + (nv << 2);
        for (int i = ts + tid; i < nch; i += 256) rowp[c0 + i] = lds[i + align_off];
        __syncthreads();  // protect lds reuse across chunks
    }
}

// ---------------------------------------------------------------------------
// Fallback kernels (only used if d_ws is too small for dsT/pcount — not
// expected on this harness).
// ---------------------------------------------------------------------------
__global__ __launch_bounds__(256) void k_match_logp_fb(
    const int* __restrict__ in_tok, const int* __restrict__ ds_tok,
    const float* __restrict__ t, float* __restrict__ logp)
{
    __shared__ int s_in[BSZ * CLEN];
    __shared__ float s_la[BSZ], s_lb[BSZ];
    const int tid = threadIdx.x;
    for (int i = tid; i < BSZ * CLEN; i += 256) s_in[i] = in_tok[i];
    if (tid < BSZ) {
        float tv = t[tid];
        s_la[tid] = logf(tv + (1.0f - tv) / (float)T_VOCAB);
        s_lb[tid] = logf((1.0f - tv) / (float)T_VOCAB);
    }
    __syncthreads();
    const int n = blockIdx.x * 256 + tid;
    int mc[BSZ] = {0, 0, 0, 0};
    const int4* row = (const int4*)(ds_tok + (size_t)n * CLEN);
    for (int j = 0; j < CLEN / 4; ++j) {
        int4 v = row[j];
        int s = 4 * j;
        #pragma unroll
        for (int b = 0; b < BSZ; ++b)
            mc[b] += (v.x == s_in[b*CLEN+s]) + (v.y == s_in[b*CLEN+s+1]) +
                     (v.z == s_in[b*CLEN+s+2]) + (v.w == s_in[b*CLEN+s+3]);
    }
    #pragma unroll
    for (int b = 0; b < BSZ; ++b) {
        float m = (float)mc[b];
        logp[b * NDATA + n] = m * s_la[b] + ((float)CLEN - m) * s_lb[b];
    }
}

__global__ __launch_bounds__(256) void k_softmax_fb(
    const float* __restrict__ logp, float* __restrict__ w)
{
    const int b = blockIdx.x;
    const int tid = threadIdx.x;
    float lp[NPT];
    float m = -INFINITY;
    #pragma unroll
    for (int k = 0; k < NPT; ++k) {
        lp[k] = logp[b * NDATA + tid + k * 256];
        m = fmaxf(m, lp[k]);
    }
    #pragma unroll
    for (int off = 32; off >= 1; off >>= 1) m = fmaxf(m, __shfl_xor(m, off));
    __shared__ float redm[4], reds[4];
    const int wid = tid >> 6;
    if ((tid & 63) == 0) redm[wid] = m;
    __syncthreads();
    const float M = fmaxf(fmaxf(redm[0], redm[1]), fmaxf(redm[2], redm[3]));
    float e[NPT];
    float sum = 0.0f;
    #pragma unroll
    for (int k = 0; k < NPT; ++k) { e[k] = expf(lp[k] - M); sum += e[k]; }
    #pragma unroll
    for (int off = 32; off >= 1; off >>= 1) sum += __shfl_xor(sum, off);
    if ((tid & 63) == 0) reds[wid] = sum;
    __syncthreads();
    const float inv = 1.0f / (reds[0] + reds[1] + reds[2] + reds[3]);
    #pragma unroll
    for (int k = 0; k < NPT; ++k) w[b * NDATA + tid + k * 256] = e[k] * inv;
}

// ---------------------------------------------------------------------------
extern "C" void kernel_launch(void* const* d_in, const int* in_sizes, int n_in,
                              void* d_out, int out_size, void* d_ws, size_t ws_size,
                              hipStream_t stream) {
    const int*   in_tok = (const int*)d_in[0];    // (BSZ, CLEN) int32
    const int*   ds_tok = (const int*)d_in[1];    // (NDATA, CLEN) int32
    const float* t      = (const float*)d_in[2];  // (BSZ,) f32
    float* out = (float*)d_out;                   // (BSZ, CLEN, T_VOCAB) f32

    int*   dsT    = (int*)d_ws;                              // CLEN*NDATA
    int*   pcount = dsT + (size_t)CLEN * NDATA;              // SLICES*BSZ*NDATA
    float* w      = (float*)(pcount + SLICES * BSZ * NDATA); // BSZ*NDATA
    float* logp   = w + BSZ * NDATA;                         // BSZ*NDATA (fallback)

    const size_t need = ((size_t)CLEN * NDATA + (size_t)SLICES * BSZ * NDATA) * sizeof(int)
                      + (size_t)2 * BSZ * NDATA * sizeof(float);

    if (ws_size >= need) {
        k_transpose<<<dim3(NDATA / 64, CLEN / 64), 256, 0, stream>>>(ds_tok, dsT);
        k_match<<<64, 256, 0, stream>>>(dsT, in_tok, pcount);
        k_weights<<<BSZ, 256, 0, stream>>>(pcount, t, w);
        k_scatter<true><<<BSZ * CLEN, 256, 0, stream>>>(ds_tok, dsT, w, out);
    } else {
        k_match_logp_fb<<<NDATA / 256, 256, 0, stream>>>(in_tok, ds_tok, t, logp);
        k_softmax_fb<<<BSZ, 256, 0, stream>>>(logp, w);
        k_scatter<false><<<BSZ * CLEN, 256, 0, stream>>>(ds_tok, dsT, w, out);
    }
}

// Round 4
// 335.801 us; speedup vs baseline: 1.0480x; 1.0257x over previous
//
#include <hip/hip_runtime.h>

// Problem constants (fixed harness shapes).
constexpr int T_VOCAB = 50265;          // vocab size
constexpr int CLEN    = 384;            // context length
constexpr int BSZ     = 4;              // batch
constexpr int NDATA   = 2048;           // dataset rows
constexpr int NPT     = NDATA / 256;    // dataset rows per thread (8)
constexpr int CHUNK   = 6720;           // floats per LDS chunk (26.25 KiB -> 6 blocks/CU)
constexpr int NCHUNK  = (T_VOCAB + CHUNK - 1) / CHUNK;  // 8
constexpr int SLICES  = CLEN / 64;      // 6 s-tiles in the fused transpose+match

typedef float f32x4 __attribute__((ext_vector_type(4)));  // native vec for nontemporal builtins

// ---------------------------------------------------------------------------
// K0: fused LDS-tiled transpose ds[N][S] -> dsT[S][N]  +  partial match
// counts per (s-tile, b, n).  Tile is already in LDS for the transpose; the
// write pass also compares each token against the (wave-uniform) input
// tokens and LDS-reduces per-n counts across the 4 quads.
// ---------------------------------------------------------------------------
__global__ __launch_bounds__(256) void k_transpose_match(
    const int* __restrict__ ds,       // [NDATA][CLEN]
    const int* __restrict__ in_tok,   // [BSZ][CLEN]
    int* __restrict__ dsT,            // [CLEN][NDATA]
    int* __restrict__ pcount)         // [SLICES][BSZ][NDATA]
{
    __shared__ int tile[64][65];      // +1 pad: conflict-free transpose
    __shared__ int s_in[BSZ][64];
    __shared__ int cnt[64][BSZ];
    const int n0   = blockIdx.x * 64; // 32 n-tiles
    const int s0   = blockIdx.y * 64; // 6 s-tiles
    const int lane = threadIdx.x & 63;
    const int quad = threadIdx.x >> 6;  // 0..3 (wave id -> wave-uniform)
    {
        const int b = quad;             // 4 waves x 64 lanes covers [4][64]
        s_in[b][lane] = in_tok[b * CLEN + s0 + lane];
        cnt[lane][b]  = 0;
    }
    #pragma unroll
    for (int k = 0; k < 16; ++k) {
        const int r = quad + 4 * k;
        tile[r][lane] = ds[(size_t)(n0 + r) * CLEN + s0 + lane];  // coalesced
    }
    __syncthreads();
    int c0 = 0, c1 = 0, c2 = 0, c3 = 0;
    #pragma unroll
    for (int k = 0; k < 16; ++k) {
        const int c = quad + 4 * k;               // wave-uniform column
        const int tok = tile[lane][c];            // conflict-free (stride 65)
        dsT[(size_t)(s0 + c) * NDATA + n0 + lane] = tok;  // coalesced
        c0 += (tok == s_in[0][c]);                // broadcast reads
        c1 += (tok == s_in[1][c]);
        c2 += (tok == s_in[2][c]);
        c3 += (tok == s_in[3][c]);
    }
    atomicAdd(&cnt[lane][0], c0);                 // reduce over 4 quads
    atomicAdd(&cnt[lane][1], c1);
    atomicAdd(&cnt[lane][2], c2);
    atomicAdd(&cnt[lane][3], c3);
    __syncthreads();
    {
        const int b = quad;
        pcount[((size_t)blockIdx.y * BSZ + b) * NDATA + n0 + lane] = cnt[lane][b];
    }
}

// ---------------------------------------------------------------------------
// K1: reduce partial counts -> logp -> stable softmax -> w.  One block per b.
// ---------------------------------------------------------------------------
__global__ __launch_bounds__(256) void k_weights(
    const int* __restrict__ pcount,   // [SLICES][BSZ][NDATA]
    const float* __restrict__ t,      // [BSZ]
    float* __restrict__ w)            // [BSZ][NDATA]
{
    const int b = blockIdx.x;
    const int tid = threadIdx.x;
    const float tv = t[b];
    const float la = logf(tv + (1.0f - tv) / (float)T_VOCAB);
    const float lb = logf((1.0f - tv) / (float)T_VOCAB);

    float lp[NPT];
    float m = -INFINITY;
    #pragma unroll
    for (int k = 0; k < NPT; ++k) {
        const int n = tid + k * 256;
        int cnt = 0;
        #pragma unroll
        for (int sl = 0; sl < SLICES; ++sl)
            cnt += pcount[(sl * BSZ + b) * NDATA + n];
        const float mc = (float)cnt;
        lp[k] = mc * la + ((float)CLEN - mc) * lb;
        m = fmaxf(m, lp[k]);
    }
    #pragma unroll
    for (int off = 32; off >= 1; off >>= 1) m = fmaxf(m, __shfl_xor(m, off));
    __shared__ float redm[4], reds[4];
    const int wid = tid >> 6;
    if ((tid & 63) == 0) redm[wid] = m;
    __syncthreads();
    const float M = fmaxf(fmaxf(redm[0], redm[1]), fmaxf(redm[2], redm[3]));

    float e[NPT];
    float sum = 0.0f;
    #pragma unroll
    for (int k = 0; k < NPT; ++k) { e[k] = expf(lp[k] - M); sum += e[k]; }
    #pragma unroll
    for (int off = 32; off >= 1; off >>= 1) sum += __shfl_xor(sum, off);
    if ((tid & 63) == 0) reds[wid] = sum;
    __syncthreads();
    const float inv = 1.0f / (reds[0] + reds[1] + reds[2] + reds[3]);
    #pragma unroll
    for (int k = 0; k < NPT; ++k) w[b * NDATA + tid + k * 256] = e[k] * inv;
}

// ---------------------------------------------------------------------------
// K2: grid = (BSZ*CLEN rows) x (NCHUNK vocab chunks).  One block builds one
// 6720-float chunk of one output row in LDS (atomicAdd handles duplicate
// tokens), then streams it out with 16B-aligned nontemporal f32x4 stores.
// No per-block chunk loop -> 2 barriers per block, store drain overlaps
// other blocks via retirement.  Token/weight re-reads are L2-resident.
// ---------------------------------------------------------------------------
template <bool USE_T>
__global__ __launch_bounds__(256) void k_scatter(
    const int* __restrict__ ds_tok,  // [NDATA][CLEN]  (fallback path)
    const int* __restrict__ dsT,     // [CLEN][NDATA]
    const float* __restrict__ w,     // [BSZ][NDATA]
    float* __restrict__ out)         // [BSZ][CLEN][T_VOCAB]
{
    __shared__ float lds[CHUNK + 4];
    const int tid = threadIdx.x;
    const int row = blockIdx.x;          // b minor: 4 consecutive blocks share s
    const int b = row & (BSZ - 1);
    const int s = row >> 2;
    const int c0 = blockIdx.y * CHUNK;
    const int nch = (T_VOCAB - c0 < CHUNK) ? (T_VOCAB - c0) : CHUNK;

    int   tok[NPT];
    float wv[NPT];
    if (USE_T) {
        // vectorized: thread covers n = tid*8 .. tid*8+7 (wave reads 2 KB contiguous)
        const int4*  tp = (const int4*)(dsT + (size_t)s * NDATA) + tid * 2;
        const f32x4* wp = (const f32x4*)(w + (size_t)b * NDATA) + tid * 2;
        int4  ta = tp[0], tb = tp[1];
        f32x4 wa = wp[0], wb = wp[1];
        tok[0] = ta.x; tok[1] = ta.y; tok[2] = ta.z; tok[3] = ta.w;
        tok[4] = tb.x; tok[5] = tb.y; tok[6] = tb.z; tok[7] = tb.w;
        wv[0] = wa.x; wv[1] = wa.y; wv[2] = wa.z; wv[3] = wa.w;
        wv[4] = wb.x; wv[5] = wb.y; wv[6] = wb.z; wv[7] = wb.w;
    } else {
        #pragma unroll
        for (int k = 0; k < NPT; ++k) {
            const int n = tid + k * 256;
            tok[k] = ds_tok[(size_t)n * CLEN + s];
            wv[k]  = w[(size_t)b * NDATA + n];
        }
    }

    const size_t row_elem0 = ((size_t)b * CLEN + s) * (size_t)T_VOCAB;
    float* rowp = out + row_elem0;
    const int align_off = (int)(row_elem0 & 3);  // lds[j+align_off] <-> row elem c0+j

    // ---- zero LDS (vectorized) ----
    const int tot = nch + align_off;
    f32x4* l4 = (f32x4*)lds;
    const int nz4 = (tot + 3) >> 2;
    for (int i = tid; i < nz4; i += 256) l4[i] = (f32x4){0.f, 0.f, 0.f, 0.f};
    __syncthreads();
    // ---- scatter this block's 2048 (token, weight) pairs ----
    #pragma unroll
    for (int k = 0; k < NPT; ++k) {
        const unsigned off = (unsigned)(tok[k] - c0);
        if (off < (unsigned)nch) atomicAdd(&lds[off + align_off], wv[k]);
    }
    __syncthreads();
    // ---- stream chunk to global: scalar head, aligned f32x4 NT body, tail ----
    int head = (4 - align_off) & 3;
    if (head > nch) head = nch;
    if (tid < head) rowp[c0 + tid] = lds[tid + align_off];
    const int nv = (nch - head) >> 2;
    const f32x4* l4s = (const f32x4*)lds + (align_off ? 1 : 0);
    f32x4* dst4 = (f32x4*)(rowp + c0 + head);
    for (int i = tid; i < nv; i += 256)
        __builtin_nontemporal_store(l4s[i], &dst4[i]);
    const int ts = head + (nv << 2);
    for (int i = ts + tid; i < nch; i += 256) rowp[c0 + i] = lds[i + align_off];
}

// ---------------------------------------------------------------------------
// Fallback kernels (only if d_ws is too small for dsT/pcount — not expected).
// ---------------------------------------------------------------------------
__global__ __launch_bounds__(256) void k_match_logp_fb(
    const int* __restrict__ in_tok, const int* __restrict__ ds_tok,
    const float* __restrict__ t, float* __restrict__ logp)
{
    __shared__ int s_in[BSZ * CLEN];
    __shared__ float s_la[BSZ], s_lb[BSZ];
    const int tid = threadIdx.x;
    for (int i = tid; i < BSZ * CLEN; i += 256) s_in[i] = in_tok[i];
    if (tid < BSZ) {
        float tv = t[tid];
        s_la[tid] = logf(tv + (1.0f - tv) / (float)T_VOCAB);
        s_lb[tid] = logf((1.0f - tv) / (float)T_VOCAB);
    }
    __syncthreads();
    const int n = blockIdx.x * 256 + tid;
    int mc[BSZ] = {0, 0, 0, 0};
    const int4* rowv = (const int4*)(ds_tok + (size_t)n * CLEN);
    for (int j = 0; j < CLEN / 4; ++j) {
        int4 v = rowv[j];
        int s = 4 * j;
        #pragma unroll
        for (int b = 0; b < BSZ; ++b)
            mc[b] += (v.x == s_in[b*CLEN+s]) + (v.y == s_in[b*CLEN+s+1]) +
                     (v.z == s_in[b*CLEN+s+2]) + (v.w == s_in[b*CLEN+s+3]);
    }
    #pragma unroll
    for (int b = 0; b < BSZ; ++b) {
        float m = (float)mc[b];
        logp[b * NDATA + n] = m * s_la[b] + ((float)CLEN - m) * s_lb[b];
    }
}

__global__ __launch_bounds__(256) void k_softmax_fb(
    const float* __restrict__ logp, float* __restrict__ w)
{
    const int b = blockIdx.x;
    const int tid = threadIdx.x;
    float lp[NPT];
    float m = -INFINITY;
    #pragma unroll
    for (int k = 0; k < NPT; ++k) {
        lp[k] = logp[b * NDATA + tid + k * 256];
        m = fmaxf(m, lp[k]);
    }
    #pragma unroll
    for (int off = 32; off >= 1; off >>= 1) m = fmaxf(m, __shfl_xor(m, off));
    __shared__ float redm[4], reds[4];
    const int wid = tid >> 6;
    if ((tid & 63) == 0) redm[wid] = m;
    __syncthreads();
    const float M = fmaxf(fmaxf(redm[0], redm[1]), fmaxf(redm[2], redm[3]));
    float e[NPT];
    float sum = 0.0f;
    #pragma unroll
    for (int k = 0; k < NPT; ++k) { e[k] = expf(lp[k] - M); sum += e[k]; }
    #pragma unroll
    for (int off = 32; off >= 1; off >>= 1) sum += __shfl_xor(sum, off);
    if ((tid & 63) == 0) reds[wid] = sum;
    __syncthreads();
    const float inv = 1.0f / (reds[0] + reds[1] + reds[2] + reds[3]);
    #pragma unroll
    for (int k = 0; k < NPT; ++k) w[b * NDATA + tid + k * 256] = e[k] * inv;
}

// ---------------------------------------------------------------------------
extern "C" void kernel_launch(void* const* d_in, const int* in_sizes, int n_in,
                              void* d_out, int out_size, void* d_ws, size_t ws_size,
                              hipStream_t stream) {
    const int*   in_tok = (const int*)d_in[0];    // (BSZ, CLEN) int32
    const int*   ds_tok = (const int*)d_in[1];    // (NDATA, CLEN) int32
    const float* t      = (const float*)d_in[2];  // (BSZ,) f32
    float* out = (float*)d_out;                   // (BSZ, CLEN, T_VOCAB) f32

    int*   dsT    = (int*)d_ws;                              // CLEN*NDATA
    int*   pcount = dsT + (size_t)CLEN * NDATA;              // SLICES*BSZ*NDATA
    float* w      = (float*)(pcount + SLICES * BSZ * NDATA); // BSZ*NDATA

    const size_t need = ((size_t)CLEN * NDATA + (size_t)SLICES * BSZ * NDATA) * sizeof(int)
                      + (size_t)BSZ * NDATA * sizeof(float);

    if (ws_size >= need) {
        k_transpose_match<<<dim3(NDATA / 64, CLEN / 64), 256, 0, stream>>>(ds_tok, in_tok, dsT, pcount);
        k_weights<<<BSZ, 256, 0, stream>>>(pcount, t, w);
        k_scatter<true><<<dim3(BSZ * CLEN, NCHUNK), 256, 0, stream>>>(ds_tok, dsT, w, out);
    } else {
        float* logp_fb = (float*)d_ws;                 // BSZ*NDATA
        float* w_fb    = logp_fb + BSZ * NDATA;        // BSZ*NDATA
        k_match_logp_fb<<<NDATA / 256, 256, 0, stream>>>(in_tok, ds_tok, t, logp_fb);
        k_softmax_fb<<<BSZ, 256, 0, stream>>>(logp_fb, w_fb);
        k_scatter<false><<<dim3(BSZ * CLEN, NCHUNK), 256, 0, stream>>>(ds_tok, (const int*)d_ws, w_fb, out);
    }
}

// Round 5
// 333.957 us; speedup vs baseline: 1.0537x; 1.0055x over previous
//
#include <hip/hip_runtime.h>

// Problem constants (fixed harness shapes).
constexpr int T_VOCAB = 50265;          // vocab size
constexpr int CLEN    = 384;            // context length
constexpr int BSZ     = 4;              // batch
constexpr int NDATA   = 2048;           // dataset rows
constexpr int NPT     = NDATA / 256;    // rows per thread in 256-thread kernels (8)
constexpr int SCT     = 512;            // scatter block size
constexpr int SNPT    = NDATA / SCT;    // rows per thread in scatter (4)
constexpr int CHUNK   = 10240;          // floats per LDS chunk (40 KiB -> 4 blocks/CU = 32 waves/CU)
constexpr int NCHUNK  = (T_VOCAB + CHUNK - 1) / CHUNK;  // 5
constexpr int SLICES  = CLEN / 64;      // 6 s-tiles in the fused transpose+match

typedef float f32x4 __attribute__((ext_vector_type(4)));  // native vec for nontemporal builtins

// ---------------------------------------------------------------------------
// K0: fused LDS-tiled transpose ds[N][S] -> dsT[S][N]  +  partial match
// counts per (s-tile, b, n).
// ---------------------------------------------------------------------------
__global__ __launch_bounds__(256) void k_transpose_match(
    const int* __restrict__ ds,       // [NDATA][CLEN]
    const int* __restrict__ in_tok,   // [BSZ][CLEN]
    int* __restrict__ dsT,            // [CLEN][NDATA]
    int* __restrict__ pcount)         // [SLICES][BSZ][NDATA]
{
    __shared__ int tile[64][65];      // +1 pad: conflict-free transpose
    __shared__ int s_in[BSZ][64];
    __shared__ int cnt[64][BSZ];
    const int n0   = blockIdx.x * 64; // 32 n-tiles
    const int s0   = blockIdx.y * 64; // 6 s-tiles
    const int lane = threadIdx.x & 63;
    const int quad = threadIdx.x >> 6;  // 0..3 (wave id -> wave-uniform)
    {
        const int b = quad;             // 4 waves x 64 lanes covers [4][64]
        s_in[b][lane] = in_tok[b * CLEN + s0 + lane];
        cnt[lane][b]  = 0;
    }
    #pragma unroll
    for (int k = 0; k < 16; ++k) {
        const int r = quad + 4 * k;
        tile[r][lane] = ds[(size_t)(n0 + r) * CLEN + s0 + lane];  // coalesced
    }
    __syncthreads();
    int c0 = 0, c1 = 0, c2 = 0, c3 = 0;
    #pragma unroll
    for (int k = 0; k < 16; ++k) {
        const int c = quad + 4 * k;               // wave-uniform column
        const int tok = tile[lane][c];            // conflict-free (stride 65)
        dsT[(size_t)(s0 + c) * NDATA + n0 + lane] = tok;  // coalesced
        c0 += (tok == s_in[0][c]);                // broadcast reads
        c1 += (tok == s_in[1][c]);
        c2 += (tok == s_in[2][c]);
        c3 += (tok == s_in[3][c]);
    }
    atomicAdd(&cnt[lane][0], c0);                 // reduce over 4 quads
    atomicAdd(&cnt[lane][1], c1);
    atomicAdd(&cnt[lane][2], c2);
    atomicAdd(&cnt[lane][3], c3);
    __syncthreads();
    {
        const int b = quad;
        pcount[((size_t)blockIdx.y * BSZ + b) * NDATA + n0 + lane] = cnt[lane][b];
    }
}

// ---------------------------------------------------------------------------
// K1: reduce partial counts -> logp -> stable softmax -> w.  One block per b.
// ---------------------------------------------------------------------------
__global__ __launch_bounds__(256) void k_weights(
    const int* __restrict__ pcount,   // [SLICES][BSZ][NDATA]
    const float* __restrict__ t,      // [BSZ]
    float* __restrict__ w)            // [BSZ][NDATA]
{
    const int b = blockIdx.x;
    const int tid = threadIdx.x;
    const float tv = t[b];
    const float la = logf(tv + (1.0f - tv) / (float)T_VOCAB);
    const float lb = logf((1.0f - tv) / (float)T_VOCAB);

    float lp[NPT];
    float m = -INFINITY;
    #pragma unroll
    for (int k = 0; k < NPT; ++k) {
        const int n = tid + k * 256;
        int cnt = 0;
        #pragma unroll
        for (int sl = 0; sl < SLICES; ++sl)
            cnt += pcount[(sl * BSZ + b) * NDATA + n];
        const float mc = (float)cnt;
        lp[k] = mc * la + ((float)CLEN - mc) * lb;
        m = fmaxf(m, lp[k]);
    }
    #pragma unroll
    for (int off = 32; off >= 1; off >>= 1) m = fmaxf(m, __shfl_xor(m, off));
    __shared__ float redm[4], reds[4];
    const int wid = tid >> 6;
    if ((tid & 63) == 0) redm[wid] = m;
    __syncthreads();
    const float M = fmaxf(fmaxf(redm[0], redm[1]), fmaxf(redm[2], redm[3]));

    float e[NPT];
    float sum = 0.0f;
    #pragma unroll
    for (int k = 0; k < NPT; ++k) { e[k] = expf(lp[k] - M); sum += e[k]; }
    #pragma unroll
    for (int off = 32; off >= 1; off >>= 1) sum += __shfl_xor(sum, off);
    if ((tid & 63) == 0) reds[wid] = sum;
    __syncthreads();
    const float inv = 1.0f / (reds[0] + reds[1] + reds[2] + reds[3]);
    #pragma unroll
    for (int k = 0; k < NPT; ++k) w[b * NDATA + tid + k * 256] = e[k] * inv;
}

// ---------------------------------------------------------------------------
// K2: grid = (BSZ*CLEN rows) x (NCHUNK vocab chunks), 512 threads.  One block
// builds one 10240-float chunk of one output row in LDS (atomicAdd handles
// duplicate tokens), then streams it out with 16B-aligned nontemporal f32x4
// stores.  40 KiB LDS -> 4 blocks/CU = 32 waves/CU (max occupancy).
// ---------------------------------------------------------------------------
template <bool USE_T>
__global__ __launch_bounds__(SCT) void k_scatter(
    const int* __restrict__ ds_tok,  // [NDATA][CLEN]  (fallback path)
    const int* __restrict__ dsT,     // [CLEN][NDATA]
    const float* __restrict__ w,     // [BSZ][NDATA]
    float* __restrict__ out)         // [BSZ][CLEN][T_VOCAB]
{
    __shared__ float lds[CHUNK + 4];
    const int tid = threadIdx.x;
    const int row = blockIdx.x;          // b minor: 4 consecutive blocks share s
    const int b = row & (BSZ - 1);
    const int s = row >> 2;
    const int c0 = blockIdx.y * CHUNK;
    const int nch = (T_VOCAB - c0 < CHUNK) ? (T_VOCAB - c0) : CHUNK;

    int   tok[SNPT];
    float wv[SNPT];
    if (USE_T) {
        // thread covers n = tid*4 .. tid*4+3 (wave reads 1 KB contiguous)
        const int4  ta = ((const int4*)(dsT + (size_t)s * NDATA))[tid];
        const f32x4 wa = ((const f32x4*)(w + (size_t)b * NDATA))[tid];
        tok[0] = ta.x; tok[1] = ta.y; tok[2] = ta.z; tok[3] = ta.w;
        wv[0] = wa.x; wv[1] = wa.y; wv[2] = wa.z; wv[3] = wa.w;
    } else {
        #pragma unroll
        for (int k = 0; k < SNPT; ++k) {
            const int n = tid + k * SCT;
            tok[k] = ds_tok[(size_t)n * CLEN + s];
            wv[k]  = w[(size_t)b * NDATA + n];
        }
    }

    const size_t row_elem0 = ((size_t)b * CLEN + s) * (size_t)T_VOCAB;
    float* rowp = out + row_elem0;
    const int align_off = (int)(row_elem0 & 3);  // lds[j+align_off] <-> row elem c0+j

    // ---- zero LDS (vectorized); global loads above are already in flight ----
    const int tot = nch + align_off;
    f32x4* l4 = (f32x4*)lds;
    const int nz4 = (tot + 3) >> 2;
    for (int i = tid; i < nz4; i += SCT) l4[i] = (f32x4){0.f, 0.f, 0.f, 0.f};
    __syncthreads();
    // ---- scatter this block's 2048 (token, weight) pairs ----
    #pragma unroll
    for (int k = 0; k < SNPT; ++k) {
        const unsigned off = (unsigned)(tok[k] - c0);
        if (off < (unsigned)nch) atomicAdd(&lds[off + align_off], wv[k]);
    }
    __syncthreads();
    // ---- stream chunk to global: NT scalar head, aligned NT f32x4 body, NT tail ----
    int head = (4 - align_off) & 3;
    if (head > nch) head = nch;
    if (tid < head) __builtin_nontemporal_store(lds[tid + align_off], &rowp[c0 + tid]);
    const int nv = (nch - head) >> 2;
    const f32x4* l4s = (const f32x4*)lds + (align_off ? 1 : 0);
    f32x4* dst4 = (f32x4*)(rowp + c0 + head);
    for (int i = tid; i < nv; i += SCT)
        __builtin_nontemporal_store(l4s[i], &dst4[i]);
    const int ts = head + (nv << 2);
    for (int i = ts + tid; i < nch; i += SCT)
        __builtin_nontemporal_store(lds[i + align_off], &rowp[c0 + i]);
}

// ---------------------------------------------------------------------------
// Fallback kernels (only if d_ws is too small for dsT/pcount — not expected).
// ---------------------------------------------------------------------------
__global__ __launch_bounds__(256) void k_match_logp_fb(
    const int* __restrict__ in_tok, const int* __restrict__ ds_tok,
    const float* __restrict__ t, float* __restrict__ logp)
{
    __shared__ int s_in[BSZ * CLEN];
    __shared__ float s_la[BSZ], s_lb[BSZ];
    const int tid = threadIdx.x;
    for (int i = tid; i < BSZ * CLEN; i += 256) s_in[i] = in_tok[i];
    if (tid < BSZ) {
        float tv = t[tid];
        s_la[tid] = logf(tv + (1.0f - tv) / (float)T_VOCAB);
        s_lb[tid] = logf((1.0f - tv) / (float)T_VOCAB);
    }
    __syncthreads();
    const int n = blockIdx.x * 256 + tid;
    int mc[BSZ] = {0, 0, 0, 0};
    const int4* rowv = (const int4*)(ds_tok + (size_t)n * CLEN);
    for (int j = 0; j < CLEN / 4; ++j) {
        int4 v = rowv[j];
        int s = 4 * j;
        #pragma unroll
        for (int b = 0; b < BSZ; ++b)
            mc[b] += (v.x == s_in[b*CLEN+s]) + (v.y == s_in[b*CLEN+s+1]) +
                     (v.z == s_in[b*CLEN+s+2]) + (v.w == s_in[b*CLEN+s+3]);
    }
    #pragma unroll
    for (int b = 0; b < BSZ; ++b) {
        float m = (float)mc[b];
        logp[b * NDATA + n] = m * s_la[b] + ((float)CLEN - m) * s_lb[b];
    }
}

__global__ __launch_bounds__(256) void k_softmax_fb(
    const float* __restrict__ logp, float* __restrict__ w)
{
    const int b = blockIdx.x;
    const int tid = threadIdx.x;
    float lp[NPT];
    float m = -INFINITY;
    #pragma unroll
    for (int k = 0; k < NPT; ++k) {
        lp[k] = logp[b * NDATA + tid + k * 256];
        m = fmaxf(m, lp[k]);
    }
    #pragma unroll
    for (int off = 32; off >= 1; off >>= 1) m = fmaxf(m, __shfl_xor(m, off));
    __shared__ float redm[4], reds[4];
    const int wid = tid >> 6;
    if ((tid & 63) == 0) redm[wid] = m;
    __syncthreads();
    const float M = fmaxf(fmaxf(redm[0], redm[1]), fmaxf(redm[2], redm[3]));
    float e[NPT];
    float sum = 0.0f;
    #pragma unroll
    for (int k = 0; k < NPT; ++k) { e[k] = expf(lp[k] - M); sum += e[k]; }
    #pragma unroll
    for (int off = 32; off >= 1; off >>= 1) sum += __shfl_xor(sum, off);
    if ((tid & 63) == 0) reds[wid] = sum;
    __syncthreads();
    const float inv = 1.0f / (reds[0] + reds[1] + reds[2] + reds[3]);
    #pragma unroll
    for (int k = 0; k < NPT; ++k) w[b * NDATA + tid + k * 256] = e[k] * inv;
}

// ---------------------------------------------------------------------------
extern "C" void kernel_launch(void* const* d_in, const int* in_sizes, int n_in,
                              void* d_out, int out_size, void* d_ws, size_t ws_size,
                              hipStream_t stream) {
    const int*   in_tok = (const int*)d_in[0];    // (BSZ, CLEN) int32
    const int*   ds_tok = (const int*)d_in[1];    // (NDATA, CLEN) int32
    const float* t      = (const float*)d_in[2];  // (BSZ,) f32
    float* out = (float*)d_out;                   // (BSZ, CLEN, T_VOCAB) f32

    int*   dsT    = (int*)d_ws;                              // CLEN*NDATA
    int*   pcount = dsT + (size_t)CLEN * NDATA;              // SLICES*BSZ*NDATA
    float* w      = (float*)(pcount + SLICES * BSZ * NDATA); // BSZ*NDATA

    const size_t need = ((size_t)CLEN * NDATA + (size_t)SLICES * BSZ * NDATA) * sizeof(int)
                      + (size_t)BSZ * NDATA * sizeof(float);

    if (ws_size >= need) {
        k_transpose_match<<<dim3(NDATA / 64, CLEN / 64), 256, 0, stream>>>(ds_tok, in_tok, dsT, pcount);
        k_weights<<<BSZ, 256, 0, stream>>>(pcount, t, w);
        k_scatter<true><<<dim3(BSZ * CLEN, NCHUNK), SCT, 0, stream>>>(ds_tok, dsT, w, out);
    } else {
        float* logp_fb = (float*)d_ws;                 // BSZ*NDATA
        float* w_fb    = logp_fb + BSZ * NDATA;        // BSZ*NDATA
        k_match_logp_fb<<<NDATA / 256, 256, 0, stream>>>(in_tok, ds_tok, t, logp_fb);
        k_softmax_fb<<<BSZ, 256, 0, stream>>>(logp_fb, w_fb);
        k_scatter<false><<<dim3(BSZ * CLEN, NCHUNK), SCT, 0, stream>>>(ds_tok, (const int*)d_ws, w_fb, out);
    }
}